// Round 4
// baseline (5407.794 us; speedup 1.0000x reference)
//
#include <hip/hip_runtime.h>
#include <math.h>

typedef _Float16 half8  __attribute__((ext_vector_type(8)));
typedef float    floatx4 __attribute__((ext_vector_type(4)));

#define MFMA16(a, b, c) __builtin_amdgcn_mfma_f32_16x16x32_f16((a), (b), (c), 0, 0, 0)

// ---------------- workspace layout (bytes) ----------------
// Decoder weights stored MFMA-fragment-linear: frag = 64 lanes x 16B = 1024B.
// frag value[lane][j] = W[col = 16*tile + (lane&15)][k = 32*s + (lane>>4)*8 + j], zero-padded.
// A wave's B-load is ONE coalesced 1KB read (global) or one conflict-free ds_read_b128 (LDS).
constexpr unsigned WJT_OFF  = 0;          // gate frags [13][3][7][64][8] f16 = 279552 B
constexpr unsigned WD1_OFF  = 279552;     // dec_w1 frags [7][7][64][8]   = 50176 B
constexpr unsigned W2F_OFF  = 329728;     // dec_w2 frags [4][4][64][8]   = 16384 B
constexpr unsigned WE1_OFF  = 346112;     // f16 [112][224] enc_w1
constexpr unsigned WE2_OFF  = 396288;     // f16 [208][128] enc_w2
constexpr unsigned WEL_OFF  = 449536;     // f16 [208][224] enc_wl
constexpr unsigned WIHC_OFF = 542720;     // f32 [624]  w_ih column (gate-padded, stride 208)
constexpr unsigned BSUM_OFF = 545216;     // f32 [624]  r,z: b_ih+b_hh ; n: b_ih
constexpr unsigned BHHN_OFF = 547712;     // f32 [208]  b_hh (n gate)
constexpr unsigned B1P_OFF  = 548544;     // f32 [112]
constexpr unsigned B2P_OFF  = 548992;     // f32 [64]
constexpr unsigned W3P_OFF  = 549248;     // f32 [64]
constexpr unsigned BE1_OFF  = 549504;     // f32 [112]
constexpr unsigned BE2_OFF  = 549952;     // f32 [208]
constexpr unsigned BEL_OFF  = 550784;     // f32 [208]
constexpr unsigned B3_OFF   = 551616;     // f32 [1] (+pad)
constexpr unsigned CT_OFF   = 551632;     // f64 [100][2] twiddles (cos,sin)/100

// ---------------- LDS layout (bytes) ----------------
// Hb   f16 [256][200] @0      (102400) h state; rows wv*32..+31 wave-private (no barrier needed)
// GB0  @102400 (21504), GB1 @123904 (21504): double-buffered gate tile (21 frags each)
// CHK  @145408 (8 x 2048): per-wave [32][32] f16 transpose chunks (wave-private)
// DECIN f32 [256] @161792 (1024)
// encoder overlay: SIG [64][208] f16 @GB0 (26624) ; CTL f64[200] @129024 (1600)
constexpr unsigned GB0_OFF   = 102400;
constexpr unsigned GB1_OFF   = 123904;
constexpr unsigned CHK_OFF   = 145408;
constexpr unsigned DECIN_OFF = 161792;
constexpr unsigned CTL_OFF   = 129024;
constexpr unsigned SMEM_BYTES = 162816;   // 1 block/CU, 8 waves = 2 waves/SIMD

__device__ __forceinline__ half8 lds_frag16(const _Float16* p) {
  union { uint4 u; half8 h; } cv;
  cv.u = *(const uint4*)p;      // ds_read_b128
  return cv.h;
}
__device__ __forceinline__ half8 g_frag(const _Float16* p) {
  union { uint4 u; half8 h; } cv;
  cv.u = *(const uint4*)p;      // global_load_dwordx4
  return cv.h;
}
__device__ __forceinline__ void gload_lds16(const _Float16* gsrc, _Float16* lds) {
  __builtin_amdgcn_global_load_lds(
      (const __attribute__((address_space(1))) unsigned int*)gsrc,
      (__attribute__((address_space(3))) unsigned int*)lds, 16, 0, 0);
}
__device__ __forceinline__ float sigm(float x) {
  return __builtin_amdgcn_rcpf(1.f + __builtin_amdgcn_exp2f(-1.44269504f * x));
}
__device__ __forceinline__ float tanh_(float x) {
  return 1.f - 2.f * __builtin_amdgcn_rcpf(1.f + __builtin_amdgcn_exp2f(2.88539008f * x));
}
// CHK swizzle (wave-private transpose buffer; breaks pow2-stride conflicts)
__device__ __forceinline__ int chk_idx(int row, int col) {
  return (row * 32 + col) ^ (((row >> 1) & 3) << 3);
}

// =================== prep: pack weights, build twiddles ===================
__global__ __launch_bounds__(256) void prep_kernel(
    const float* __restrict__ enc_w1, const float* __restrict__ enc_b1,
    const float* __restrict__ enc_w2, const float* __restrict__ enc_b2,
    const float* __restrict__ enc_wl, const float* __restrict__ enc_bl,
    const float* __restrict__ w_ih,  const float* __restrict__ w_hh,
    const float* __restrict__ b_ih,  const float* __restrict__ b_hh,
    const float* __restrict__ dw1, const float* __restrict__ db1,
    const float* __restrict__ dw2, const float* __restrict__ db2,
    const float* __restrict__ dw3, const float* __restrict__ db3,
    unsigned char* __restrict__ ws)
{
  const int g = blockIdx.x * blockDim.x + threadIdx.x;
  const int st = gridDim.x * blockDim.x;
  // gate frags [13][3][7][64][8]
  _Float16* WJT = (_Float16*)(ws + WJT_OFF);
  for (int i = g; i < 13 * 10752; i += st) {
    int jt = i / 10752, r1 = i - jt * 10752;
    int gg = r1 / 3584,  r2 = r1 - gg * 3584;
    int s  = r2 / 512,   r3 = r2 - s * 512;
    int ln = r3 >> 3, j = r3 & 7;
    int col = jt * 16 + (ln & 15);
    int kk  = s * 32 + (ln >> 4) * 8 + j;
    WJT[i] = (_Float16)((col < 200 && kk < 200) ? w_hh[(gg * 200 + col) * 200 + kk] : 0.f);
  }
  // dec_w1 frags [7][7][64][8]
  _Float16* WD1 = (_Float16*)(ws + WD1_OFF);
  for (int i = g; i < 7 * 3584; i += st) {
    int t = i / 3584, r1 = i - t * 3584;
    int s = r1 / 512, r3 = r1 - s * 512;
    int ln = r3 >> 3, j = r3 & 7;
    int col = t * 16 + (ln & 15);
    int kk  = s * 32 + (ln >> 4) * 8 + j;
    WD1[i] = (_Float16)((col < 100 && kk < 200) ? dw1[col * 200 + kk] : 0.f);
  }
  // dec_w2 frags [4][4][64][8]
  _Float16* W2F = (_Float16*)(ws + W2F_OFF);
  for (int i = g; i < 4 * 2048; i += st) {
    int j2 = i / 2048, r1 = i - j2 * 2048;
    int s2 = r1 / 512, r3 = r1 - s2 * 512;
    int ln = r3 >> 3, j = r3 & 7;
    int col = j2 * 16 + (ln & 15);
    int kk  = s2 * 32 + (ln >> 4) * 8 + j;
    W2F[i] = (_Float16)((col < 50 && kk < 100) ? dw2[col * 100 + kk] : 0.f);
  }
  _Float16* We1 = (_Float16*)(ws + WE1_OFF);
  for (int i = g; i < 112 * 224; i += st) {
    int r = i / 224, k = i - r * 224;
    We1[i] = (_Float16)((r < 100 && k < 202) ? enc_w1[r * 202 + k] : 0.f);
  }
  _Float16* We2 = (_Float16*)(ws + WE2_OFF);
  for (int i = g; i < 208 * 128; i += st) {
    int r = i / 128, k = i - r * 128;
    We2[i] = (_Float16)((r < 202 && k < 100) ? enc_w2[r * 100 + k] : 0.f);
  }
  _Float16* Wel = (_Float16*)(ws + WEL_OFF);
  for (int i = g; i < 208 * 224; i += st) {
    int r = i / 224, k = i - r * 224;
    Wel[i] = (_Float16)((r < 200 && k < 202) ? enc_wl[r * 202 + k] : 0.f);
  }
  float* wihc = (float*)(ws + WIHC_OFF);
  float* bsum = (float*)(ws + BSUM_OFF);
  for (int i = g; i < 624; i += st) {
    int gg = i / 208, j = i - gg * 208;
    wihc[i] = (j < 200) ? w_ih[gg * 200 + j] : 0.f;
    float b = 0.f;
    if (j < 200) b = (gg < 2) ? (b_ih[gg * 200 + j] + b_hh[gg * 200 + j]) : b_ih[400 + j];
    bsum[i] = b;
  }
  float* bhhn = (float*)(ws + BHHN_OFF);
  for (int i = g; i < 208; i += st) bhhn[i] = (i < 200) ? b_hh[400 + i] : 0.f;
  float* b1p = (float*)(ws + B1P_OFF);
  for (int i = g; i < 112; i += st) b1p[i] = (i < 100) ? db1[i] : 0.f;
  float* b2p = (float*)(ws + B2P_OFF);
  for (int i = g; i < 64; i += st) b2p[i] = (i < 50) ? db2[i] : 0.f;
  float* w3p = (float*)(ws + W3P_OFF);
  for (int i = g; i < 64; i += st) w3p[i] = (i < 50) ? dw3[i] : 0.f;
  float* be1 = (float*)(ws + BE1_OFF);
  for (int i = g; i < 112; i += st) be1[i] = (i < 100) ? enc_b1[i] : 0.f;
  float* be2 = (float*)(ws + BE2_OFF);
  for (int i = g; i < 208; i += st) be2[i] = (i < 202) ? enc_b2[i] : 0.f;
  float* bel = (float*)(ws + BEL_OFF);
  for (int i = g; i < 208; i += st) bel[i] = (i < 200) ? enc_bl[i] : 0.f;
  if (g == 0) *(float*)(ws + B3_OFF) = db3[0];
  double* ct = (double*)(ws + CT_OFF);
  for (int m = g; m < 100; m += st) {
    double c, s;
    if      (m == 0)  { c = 1.0;  s = 0.0; }
    else if (m == 25) { c = 0.0;  s = -1.0; }
    else if (m == 50) { c = -1.0; s = 0.0; }
    else if (m == 75) { c = 0.0;  s = 1.0; }
    else { double a = -2.0 * 3.14159265358979323846 * (double)m / 100.0; c = cos(a); s = sin(a); }
    ct[2 * m]     = c * 0.01;
    ct[2 * m + 1] = s * 0.01;
  }
}

// =================== fused encoder + low-sync GRU decoder ===================
// 512 thr (8 waves, 2/SIMD), 256 rows/block, 1 block/CU. Decoder sync points: 14/k-iter
// (was 22): y-path is barrier-free (B-frags from L2-resident global, CHK/DECIN wave-private);
// gate tiles LDS-staged (x8 dedup), double-buffered, jt0 staging hidden under the y-path.
__global__ __launch_bounds__(512, 1) void fused_kernel(
    const float* __restrict__ enc_in, const unsigned char* __restrict__ ws,
    float* __restrict__ out)
{
  __shared__ __align__(16) unsigned char smem[SMEM_BYTES];
  _Float16* Hb    = (_Float16*)smem;                       // [256][200]
  _Float16* GB0   = (_Float16*)(smem + GB0_OFF);
  _Float16* GB1   = (_Float16*)(smem + GB1_OFF);
  float*    DECIN = (float*)(smem + DECIN_OFF);            // [256]
  double*   CTL   = (double*)(smem + CTL_OFF);             // encoder-time

  const _Float16* WJTp = (const _Float16*)(ws + WJT_OFF);
  const _Float16* WD1f = (const _Float16*)(ws + WD1_OFF);
  const _Float16* W2f  = (const _Float16*)(ws + W2F_OFF);
  const _Float16* We1  = (const _Float16*)(ws + WE1_OFF);
  const _Float16* We2  = (const _Float16*)(ws + WE2_OFF);
  const _Float16* Wel  = (const _Float16*)(ws + WEL_OFF);
  const float* wihc = (const float*)(ws + WIHC_OFF);
  const float* bsum = (const float*)(ws + BSUM_OFF);
  const float* bhhn = (const float*)(ws + BHHN_OFF);
  const float* b1p  = (const float*)(ws + B1P_OFF);
  const float* b2p  = (const float*)(ws + B2P_OFF);
  const float* w3p  = (const float*)(ws + W3P_OFF);
  const float* be1  = (const float*)(ws + BE1_OFF);
  const float* be2  = (const float*)(ws + BE2_OFF);
  const float* bel  = (const float*)(ws + BEL_OFF);
  const float b3v   = *(const float*)(ws + B3_OFF);

  const int tid = threadIdx.x;
  const int lane = tid & 63, wv = tid >> 6;     // 8 waves
  const int q = lane >> 4, c = lane & 15;
  const int lf = lane * 8;                      // this lane's f16 offset inside a frag
  const int row0 = blockIdx.x * 256;
  const half8 Z8 = {};

  // twiddles -> LDS
  {
    const double* ctg = (const double*)(ws + CT_OFF);
    for (int i = tid; i < 200; i += 512) CTL[i] = ctg[i];
  }

  // ---------------- ENCODER: 4 sub-rounds of 64 rows (cooperative) ----------------
#pragma unroll 1
  for (int sub = 0; sub < 4; ++sub) {
    float*    XF  = (float*)(smem + sub * 25600);          // [64][100] in Hb quarter
    _Float16* X1  = (_Float16*)(smem + sub * 25600);       // [64][104] overlays after DFT
    _Float16* SIG = (_Float16*)(smem + GB0_OFF);           // [64][208]; X2 overlays
    __syncthreads();
    for (int i = tid; i < 6400; i += 512) {
      int r = i / 100, t = i - r * 100;
      XF[r * 100 + t] = enc_in[(size_t)(row0 + sub * 64 + r) * 100 + t];
    }
    for (int i = tid; i < 64 * 6; i += 512) {              // zero SIG pad cols 202..207
      int r = i / 6; SIG[r * 208 + 202 + (i - r * 6)] = (_Float16)0.f;
    }
    __syncthreads();
    // fp64 DFT; lane = row, wave-uniform bin
    for (int kb = wv; kb < 51; kb += 8) {
      double re = 0.0, im = 0.0; int m = 0;
      const float* xr = XF + lane * 100;
      for (int t = 0; t < 100; ++t) {
        double x = (double)xr[t];
        re = fma(x, CTL[2 * m], re);
        im = fma(x, CTL[2 * m + 1], im);
        m += kb; if (m >= 100) m -= 100;
      }
      if (kb == 0 || kb == 50) im = 0.0;
      float ab = (float)sqrt(re * re + im * im);
      float an = atan2f((float)im, (float)re);
      SIG[lane * 208 + 100 + kb] = (_Float16)ab;
      SIG[lane * 208 + 151 + kb] = (_Float16)an;
    }
    for (int i = tid; i < 6400; i += 512) {
      int r = i / 100, t = i - r * 100;
      SIG[r * 208 + t] = (_Float16)XF[r * 100 + t];
    }
    __syncthreads();
    // enc1: sig(K208) -> x1
#pragma unroll 1
    for (int jt = wv; jt < 7; jt += 8) {
      floatx4 C[4] = {{0,0,0,0},{0,0,0,0},{0,0,0,0},{0,0,0,0}};
      const _Float16* wp = We1 + (jt * 16 + c) * 224 + q * 8;
#pragma unroll
      for (int s = 0; s < 7; ++s) {
        half8 B = g_frag(wp + s * 32);
#pragma unroll
        for (int m = 0; m < 4; ++m) {
          half8 Af = (s == 6 && q >= 2) ? Z8 : lds_frag16(SIG + (m * 16 + c) * 208 + q * 8 + s * 32);
          C[m] = MFMA16(Af, B, C[m]);
        }
      }
      int col = jt * 16 + c; float bv = be1[col]; bool wm = col < 104;
#pragma unroll
      for (int m = 0; m < 4; ++m)
#pragma unroll
        for (int r = 0; r < 4; ++r) {
          float v = C[m][r] + bv; v = fmaxf(v, 0.01f * v);
          if (wm) X1[(m * 16 + 4 * q + r) * 104 + col] = (_Float16)v;
        }
    }
    __syncthreads();
    // enc2: x1(K104) -> x2 (overlays SIG)
#pragma unroll 1
    for (int jt = wv; jt < 13; jt += 8) {
      floatx4 C[4] = {{0,0,0,0},{0,0,0,0},{0,0,0,0},{0,0,0,0}};
      const _Float16* wp = We2 + (jt * 16 + c) * 128 + q * 8;
#pragma unroll
      for (int s = 0; s < 4; ++s) {
        half8 B = g_frag(wp + s * 32);
#pragma unroll
        for (int m = 0; m < 4; ++m) {
          half8 Af = (s == 3 && q >= 1) ? Z8 : lds_frag16(X1 + (m * 16 + c) * 104 + q * 8 + s * 32);
          C[m] = MFMA16(Af, B, C[m]);
        }
      }
      int col = jt * 16 + c; float bv = be2[col];
#pragma unroll
      for (int m = 0; m < 4; ++m)
#pragma unroll
        for (int r = 0; r < 4; ++r) {
          float v = C[m][r] + bv; v = fmaxf(v, 0.01f * v);
          SIG[(m * 16 + 4 * q + r) * 208 + col] = (_Float16)v;   // X2
        }
    }
    __syncthreads();
    // encl: x2(K208) -> h0 rows
#pragma unroll 1
    for (int jt = wv; jt < 13; jt += 8) {
      floatx4 C[4] = {{0,0,0,0},{0,0,0,0},{0,0,0,0},{0,0,0,0}};
      const _Float16* wp = Wel + (jt * 16 + c) * 224 + q * 8;
#pragma unroll
      for (int s = 0; s < 7; ++s) {
        half8 B = g_frag(wp + s * 32);
#pragma unroll
        for (int m = 0; m < 4; ++m) {
          half8 Af = (s == 6 && q >= 2) ? Z8 : lds_frag16(SIG + (m * 16 + c) * 208 + q * 8 + s * 32);
          C[m] = MFMA16(Af, B, C[m]);
        }
      }
      int col = jt * 16 + c; float bv = bel[col]; bool wm = col < 200;
#pragma unroll
      for (int m = 0; m < 4; ++m)
#pragma unroll
        for (int r = 0; r < 4; ++r) {
          float v = C[m][r] + bv;
          if (wm) Hb[(sub * 64 + m * 16 + 4 * q + r) * 200 + col] = (_Float16)v;
        }
    }
  }
  // DECIN init (no pad-zero needed: weight frags carry explicit zeros for k>=200)
  for (int i = tid; i < 256; i += 512)
    DECIN[i] = enc_in[(size_t)(row0 + i) * 100 + 99];
  __syncthreads();   // encoder h0 + DECIN visible to all waves

  _Float16* myCHK = (_Float16*)(smem + CHK_OFF) + wv * 1024;   // [32][32] f16, wave-private

  // ---------------- DECODER ----------------
#pragma unroll 1
  for (int k = 0; k <= 50; ++k) {
    // A-frags of h_k (own rows, wave-private -> no barrier). Over-reads past col 200 hit
    // neighboring finite f16 data and multiply against explicit zero weight-frag slots.
    half8 A[2][7];
#pragma unroll
    for (int m = 0; m < 2; ++m)
#pragma unroll
      for (int s = 0; s < 7; ++s)
        A[m][s] = lds_frag16(Hb + (wv * 32 + m * 16 + c) * 200 + s * 32 + q * 8);

    __syncthreads();                 // all waves done reading GB tiles of k-1
    if (k <= 49)                     // stage jt0 now; latency hides under barrier-free y-path
      for (int i = wv; i < 21; i += 8)
        gload_lds16(WJTp + i * 512 + lf, GB0 + i * 512);

    if (k >= 1) {
      // ---- y1: B-frags straight from L2 (frag-linear, coalesced); CHK transpose wave-private ----
      half8 A2[2][4];
#pragma unroll
      for (int t = 0; t < 7; ++t) {
        floatx4 C[2] = {{0,0,0,0},{0,0,0,0}};
#pragma unroll
        for (int s = 0; s < 7; ++s) {
          half8 B = g_frag(WD1f + (t * 7 + s) * 512 + lf);
#pragma unroll
          for (int m = 0; m < 2; ++m) C[m] = MFMA16(A[m][s], B, C[m]);
        }
        int col = t * 16 + c; float bv = b1p[col];
#pragma unroll
        for (int m = 0; m < 2; ++m)
#pragma unroll
          for (int r = 0; r < 4; ++r) {
            float v = C[m][r] + bv; v = fmaxf(v, 0.01f * v);
            myCHK[chk_idx(m * 16 + 4 * q + r, (t & 1) * 16 + c)] = (_Float16)v;
          }
        if (t & 1) {
#pragma unroll
          for (int m = 0; m < 2; ++m)
            A2[m][t >> 1] = lds_frag16(myCHK + chk_idx(m * 16 + c, q * 8));
        }
        if (t == 6) {
#pragma unroll
          for (int m = 0; m < 2; ++m)
            A2[m][3] = lds_frag16(myCHK + chk_idx(m * 16 + c, q * 8));
        }
      }
      // ---- y2 -> y3 (W2 frags from L2) ----
      float ya[2][4] = {{0,0,0,0},{0,0,0,0}};
#pragma unroll
      for (int jt2 = 0; jt2 < 4; ++jt2) {
        floatx4 Cy[2] = {{0,0,0,0},{0,0,0,0}};
#pragma unroll
        for (int s2 = 0; s2 < 4; ++s2) {
          half8 B = g_frag(W2f + (jt2 * 4 + s2) * 512 + lf);
#pragma unroll
          for (int m = 0; m < 2; ++m) Cy[m] = MFMA16(A2[m][s2], B, Cy[m]);
        }
        int col2 = jt2 * 16 + c; float b2v = b2p[col2], w3v = w3p[col2];
#pragma unroll
        for (int m = 0; m < 2; ++m)
#pragma unroll
          for (int r = 0; r < 4; ++r) {
            float v = Cy[m][r] + b2v; v = fmaxf(v, 0.01f * v);
            ya[m][r] = fmaf(v, w3v, ya[m][r]);
          }
      }
#pragma unroll
      for (int m = 0; m < 2; ++m)
#pragma unroll
        for (int r = 0; r < 4; ++r) {
          float v = ya[m][r];
          v += __shfl_xor(v, 1); v += __shfl_xor(v, 2);
          v += __shfl_xor(v, 4); v += __shfl_xor(v, 8);
          if (c == 0) {
            int rowL = wv * 32 + m * 16 + 4 * q + r;
            float y = v + b3v;
            DECIN[rowL] = y;                       // wave-private rows -> no barrier
            out[(size_t)(row0 + rowL) * 50 + (k - 1)] = y;
          }
        }
    }
    if (k <= 49) {
      // ---- 3-gate GEMM: 13 jt, LDS double-buffered, 1 barrier each ----
      float dreg[8];
#pragma unroll
      for (int m = 0; m < 2; ++m)
#pragma unroll
        for (int r = 0; r < 4; ++r)
          dreg[m * 4 + r] = DECIN[wv * 32 + m * 16 + 4 * q + r];
#pragma unroll 1
      for (int jt = 0; jt < 13; ++jt) {
        __syncthreads();                          // gb[jt&1] staged; gb[(jt+1)&1] free
        if (jt < 12) {
          _Float16* dst = ((jt + 1) & 1) ? GB1 : GB0;
          const _Float16* src = WJTp + (jt + 1) * 10752;
          for (int i = wv; i < 21; i += 8)
            gload_lds16(src + i * 512 + lf, dst + i * 512);
        }
        const _Float16* buf = (jt & 1) ? GB1 : GB0;
        floatx4 Cr[2] = {{0,0,0,0},{0,0,0,0}};
        floatx4 Cz[2] = {{0,0,0,0},{0,0,0,0}};
        floatx4 Cn[2] = {{0,0,0,0},{0,0,0,0}};
#pragma unroll
        for (int s = 0; s < 7; ++s) {
          half8 Br = lds_frag16(buf + s * 512 + lf);
          half8 Bz = lds_frag16(buf + (7 + s) * 512 + lf);
          half8 Bn = lds_frag16(buf + (14 + s) * 512 + lf);
#pragma unroll
          for (int m = 0; m < 2; ++m) {
            Cr[m] = MFMA16(A[m][s], Br, Cr[m]);
            Cz[m] = MFMA16(A[m][s], Bz, Cz[m]);
            Cn[m] = MFMA16(A[m][s], Bn, Cn[m]);
          }
        }
        int col = jt * 16 + c;
        float wr = wihc[col], wz = wihc[208 + col], wn = wihc[416 + col];
        float br = bsum[col], bz = bsum[208 + col], bnih = bsum[416 + col];
        float bnhh = bhhn[col];
        bool wm = col < 200;
#pragma unroll
        for (int m = 0; m < 2; ++m) {
          _Float16* hp = Hb + (wv * 32 + m * 16 + 4 * q) * 200 + col;
#pragma unroll
          for (int r = 0; r < 4; ++r) {
            float d  = dreg[m * 4 + r];
            float ho = (float)hp[r * 200];
            float rgate = sigm(Cr[m][r] + fmaf(d, wr, br));
            float zgate = sigm(Cz[m][r] + fmaf(d, wz, bz));
            float ngate = tanh_(fmaf(d, wn, bnih) + rgate * (Cn[m][r] + bnhh));
            float hv = fmaf(zgate, ho - ngate, ngate);
            if (wm) hp[r * 200] = (_Float16)hv;
          }
        }
      }
    }
  }
}

extern "C" void kernel_launch(void* const* d_in, const int* in_sizes, int n_in,
                              void* d_out, int out_size, void* d_ws, size_t ws_size,
                              hipStream_t stream) {
  const float* enc_in = (const float*)d_in[0];
  const float* enc_w1 = (const float*)d_in[1];
  const float* enc_b1 = (const float*)d_in[2];
  const float* enc_w2 = (const float*)d_in[3];
  const float* enc_b2 = (const float*)d_in[4];
  const float* enc_wl = (const float*)d_in[5];
  const float* enc_bl = (const float*)d_in[6];
  const float* w_ih   = (const float*)d_in[7];
  const float* w_hh   = (const float*)d_in[8];
  const float* b_ih   = (const float*)d_in[9];
  const float* b_hh   = (const float*)d_in[10];
  const float* dw1    = (const float*)d_in[11];
  const float* db1    = (const float*)d_in[12];
  const float* dw2    = (const float*)d_in[13];
  const float* db2    = (const float*)d_in[14];
  const float* dw3    = (const float*)d_in[15];
  const float* db3    = (const float*)d_in[16];
  unsigned char* ws = (unsigned char*)d_ws;
  float* out = (float*)d_out;

  prep_kernel<<<dim3(256), dim3(256), 0, stream>>>(
      enc_w1, enc_b1, enc_w2, enc_b2, enc_wl, enc_bl,
      w_ih, w_hh, b_ih, b_hh, dw1, db1, dw2, db2, dw3, db3, ws);
  fused_kernel<<<dim3(512), dim3(512), 0, stream>>>(enc_in, ws, out);
}

// Round 6
// 4911.551 us; speedup vs baseline: 1.1010x; 1.1010x over previous
//
#include <hip/hip_runtime.h>
#include <math.h>

typedef _Float16 half8  __attribute__((ext_vector_type(8)));
typedef float    floatx4 __attribute__((ext_vector_type(4)));

#define MFMA16(a, b, c) __builtin_amdgcn_mfma_f32_16x16x32_f16((a), (b), (c), 0, 0, 0)

// ---------------- workspace layout (bytes) ----------------
// Decoder weights stored MFMA-fragment-linear: frag = 64 lanes x 16B = 1024B.
// frag value[lane][j] = W[col = 16*tile + (lane&15)][k = 32*s + (lane>>4)*8 + j], zero-padded.
constexpr unsigned WJT_OFF  = 0;          // gate frags [13][3][7][64][8] f16 = 279552 B
constexpr unsigned WD1_OFF  = 279552;     // dec_w1 frags [7][7][64][8]   = 50176 B
constexpr unsigned W2F_OFF  = 329728;     // dec_w2 frags [4][4][64][8]   = 16384 B
constexpr unsigned WE1_OFF  = 346112;     // f16 [112][224] enc_w1
constexpr unsigned WE2_OFF  = 396288;     // f16 [208][128] enc_w2
constexpr unsigned WEL_OFF  = 449536;     // f16 [208][224] enc_wl
constexpr unsigned WIHC_OFF = 542720;     // f32 [624]  w_ih column (gate-padded, stride 208)
constexpr unsigned BSUM_OFF = 545216;     // f32 [624]  r,z: b_ih+b_hh ; n: b_ih
constexpr unsigned BHHN_OFF = 547712;     // f32 [208]  b_hh (n gate)
constexpr unsigned B1P_OFF  = 548544;     // f32 [112]
constexpr unsigned B2P_OFF  = 548992;     // f32 [64]
constexpr unsigned W3P_OFF  = 549248;     // f32 [64]
constexpr unsigned BE1_OFF  = 549504;     // f32 [112]
constexpr unsigned BE2_OFF  = 549952;     // f32 [208]
constexpr unsigned BEL_OFF  = 550784;     // f32 [208]
constexpr unsigned B3_OFF   = 551616;     // f32 [1] (+pad)
constexpr unsigned CT_OFF   = 551632;     // f64 [100][2] twiddles (cos,sin)/100

// ---------------- LDS layout (bytes) ----------------
// Hb   f16 [256][200] @0      (102400) h state, PLAIN indexing (NO swizzle: stride 200 has an
//      odd number of 8-blocks, so a bit3-XOR is NOT closed within a row -- R5's aliasing bug).
// GB   @102400 (21504)  single-buffered gate tile (21 frags)
// WB0  @123904 (7168), WB1 @131072 (7168): double-buffered dec_w1 tile (7 frags)
// CHK  @138240 (16 x 1024): per-wave [16][32] f16 transpose chunks (wave-private, swizzled)
// DECIN f32 [256] @154624 (1024)
// encoder overlay: XF f32[64][101] @102400 ; X1 f16[64][104] @102400 (post-DFT) ;
//                  SIG f16[64][208] @128256 (dead regions during encoder)
constexpr unsigned GB_OFF    = 102400;
constexpr unsigned WB0_OFF   = 123904;
constexpr unsigned WB1_OFF   = 131072;
constexpr unsigned CHK_OFF   = 138240;
constexpr unsigned DECIN_OFF = 154624;
constexpr unsigned XF_OFF    = 102400;
constexpr unsigned SIG_OFF   = 128256;
constexpr unsigned SMEM_BYTES = 155648;   // 1 block/CU, 16 waves = 4 waves/SIMD

__device__ __forceinline__ half8 lds_frag16(const _Float16* p) {
  union { uint4 u; half8 h; } cv;
  cv.u = *(const uint4*)p;      // ds_read_b128
  return cv.h;
}
__device__ __forceinline__ half8 g_frag(const _Float16* p) {
  union { uint4 u; half8 h; } cv;
  cv.u = *(const uint4*)p;      // global_load_dwordx4
  return cv.h;
}
__device__ __forceinline__ void gload_lds16(const _Float16* gsrc, _Float16* lds) {
  __builtin_amdgcn_global_load_lds(
      (const __attribute__((address_space(1))) unsigned int*)gsrc,
      (__attribute__((address_space(3))) unsigned int*)lds, 16, 0, 0);
}
__device__ __forceinline__ float sigm(float x) {
  return __builtin_amdgcn_rcpf(1.f + __builtin_amdgcn_exp2f(-1.44269504f * x));
}
__device__ __forceinline__ float tanh_(float x) {
  return 1.f - 2.f * __builtin_amdgcn_rcpf(1.f + __builtin_amdgcn_exp2f(2.88539008f * x));
}
// CHK swizzle (wave-private [16][32] transpose buffer; 32 cols = even # of 8-blocks -> closed)
__device__ __forceinline__ int chk_idx(int row, int col) {
  return (row * 32 + col) ^ (((row >> 1) & 3) << 3);
}

// =================== prep: pack weights, build twiddles ===================
__global__ __launch_bounds__(256) void prep_kernel(
    const float* __restrict__ enc_w1, const float* __restrict__ enc_b1,
    const float* __restrict__ enc_w2, const float* __restrict__ enc_b2,
    const float* __restrict__ enc_wl, const float* __restrict__ enc_bl,
    const float* __restrict__ w_ih,  const float* __restrict__ w_hh,
    const float* __restrict__ b_ih,  const float* __restrict__ b_hh,
    const float* __restrict__ dw1, const float* __restrict__ db1,
    const float* __restrict__ dw2, const float* __restrict__ db2,
    const float* __restrict__ dw3, const float* __restrict__ db3,
    unsigned char* __restrict__ ws)
{
  const int g = blockIdx.x * blockDim.x + threadIdx.x;
  const int st = gridDim.x * blockDim.x;
  // gate frags [13][3][7][64][8]
  _Float16* WJT = (_Float16*)(ws + WJT_OFF);
  for (int i = g; i < 13 * 10752; i += st) {
    int jt = i / 10752, r1 = i - jt * 10752;
    int gg = r1 / 3584,  r2 = r1 - gg * 3584;
    int s  = r2 / 512,   r3 = r2 - s * 512;
    int ln = r3 >> 3, j = r3 & 7;
    int col = jt * 16 + (ln & 15);
    int kk  = s * 32 + (ln >> 4) * 8 + j;
    WJT[i] = (_Float16)((col < 200 && kk < 200) ? w_hh[(gg * 200 + col) * 200 + kk] : 0.f);
  }
  // dec_w1 frags [7][7][64][8]
  _Float16* WD1 = (_Float16*)(ws + WD1_OFF);
  for (int i = g; i < 7 * 3584; i += st) {
    int t = i / 3584, r1 = i - t * 3584;
    int s = r1 / 512, r3 = r1 - s * 512;
    int ln = r3 >> 3, j = r3 & 7;
    int col = t * 16 + (ln & 15);
    int kk  = s * 32 + (ln >> 4) * 8 + j;
    WD1[i] = (_Float16)((col < 100 && kk < 200) ? dw1[col * 200 + kk] : 0.f);
  }
  // dec_w2 frags [4][4][64][8]
  _Float16* W2F = (_Float16*)(ws + W2F_OFF);
  for (int i = g; i < 4 * 2048; i += st) {
    int j2 = i / 2048, r1 = i - j2 * 2048;
    int s2 = r1 / 512, r3 = r1 - s2 * 512;
    int ln = r3 >> 3, j = r3 & 7;
    int col = j2 * 16 + (ln & 15);
    int kk  = s2 * 32 + (ln >> 4) * 8 + j;
    W2F[i] = (_Float16)((col < 50 && kk < 100) ? dw2[col * 100 + kk] : 0.f);
  }
  _Float16* We1 = (_Float16*)(ws + WE1_OFF);
  for (int i = g; i < 112 * 224; i += st) {
    int r = i / 224, k = i - r * 224;
    We1[i] = (_Float16)((r < 100 && k < 202) ? enc_w1[r * 202 + k] : 0.f);
  }
  _Float16* We2 = (_Float16*)(ws + WE2_OFF);
  for (int i = g; i < 208 * 128; i += st) {
    int r = i / 128, k = i - r * 128;
    We2[i] = (_Float16)((r < 202 && k < 100) ? enc_w2[r * 100 + k] : 0.f);
  }
  _Float16* Wel = (_Float16*)(ws + WEL_OFF);
  for (int i = g; i < 208 * 224; i += st) {
    int r = i / 224, k = i - r * 224;
    Wel[i] = (_Float16)((r < 200 && k < 202) ? enc_wl[r * 202 + k] : 0.f);
  }
  float* wihc = (float*)(ws + WIHC_OFF);
  float* bsum = (float*)(ws + BSUM_OFF);
  for (int i = g; i < 624; i += st) {
    int gg = i / 208, j = i - gg * 208;
    wihc[i] = (j < 200) ? w_ih[gg * 200 + j] : 0.f;
    float b = 0.f;
    if (j < 200) b = (gg < 2) ? (b_ih[gg * 200 + j] + b_hh[gg * 200 + j]) : b_ih[400 + j];
    bsum[i] = b;
  }
  float* bhhn = (float*)(ws + BHHN_OFF);
  for (int i = g; i < 208; i += st) bhhn[i] = (i < 200) ? b_hh[400 + i] : 0.f;
  float* b1p = (float*)(ws + B1P_OFF);
  for (int i = g; i < 112; i += st) b1p[i] = (i < 100) ? db1[i] : 0.f;
  float* b2p = (float*)(ws + B2P_OFF);
  for (int i = g; i < 64; i += st) b2p[i] = (i < 50) ? db2[i] : 0.f;
  float* w3p = (float*)(ws + W3P_OFF);
  for (int i = g; i < 64; i += st) w3p[i] = (i < 50) ? dw3[i] : 0.f;
  float* be1 = (float*)(ws + BE1_OFF);
  for (int i = g; i < 112; i += st) be1[i] = (i < 100) ? enc_b1[i] : 0.f;
  float* be2 = (float*)(ws + BE2_OFF);
  for (int i = g; i < 208; i += st) be2[i] = (i < 202) ? enc_b2[i] : 0.f;
  float* bel = (float*)(ws + BEL_OFF);
  for (int i = g; i < 208; i += st) bel[i] = (i < 200) ? enc_bl[i] : 0.f;
  if (g == 0) *(float*)(ws + B3_OFF) = db3[0];
  double* ct = (double*)(ws + CT_OFF);
  for (int m = g; m < 100; m += st) {
    double c, s;
    if      (m == 0)  { c = 1.0;  s = 0.0; }
    else if (m == 25) { c = 0.0;  s = -1.0; }
    else if (m == 50) { c = -1.0; s = 0.0; }
    else if (m == 75) { c = 0.0;  s = 1.0; }
    else { double a = -2.0 * 3.14159265358979323846 * (double)m / 100.0; c = cos(a); s = sin(a); }
    ct[2 * m]     = c * 0.01;
    ct[2 * m + 1] = s * 0.01;
  }
}

// =================== fused encoder + 16-wave GRU decoder ===================
// 1024 thr (16 waves, 4/SIMD = 2x occupancy vs rounds 0-4), 256 rows/block,
// 16 rows per wave (wave-private). Gate tiles LDS single-buffered (frag-linear);
// dec_w1 LDS double-buffered; dec_w2 from L2 (16 frags/iter).
__global__ __launch_bounds__(1024, 1) void fused_kernel(
    const float* __restrict__ enc_in, const unsigned char* __restrict__ ws,
    float* __restrict__ out)
{
  __shared__ __align__(16) unsigned char smem[SMEM_BYTES];
  _Float16* Hb    = (_Float16*)smem;                       // [256][200] plain
  _Float16* GB    = (_Float16*)(smem + GB_OFF);
  _Float16* WB0   = (_Float16*)(smem + WB0_OFF);
  _Float16* WB1   = (_Float16*)(smem + WB1_OFF);
  float*    DECIN = (float*)(smem + DECIN_OFF);            // [256]

  const _Float16* WJTp = (const _Float16*)(ws + WJT_OFF);
  const _Float16* WD1f = (const _Float16*)(ws + WD1_OFF);
  const _Float16* W2f  = (const _Float16*)(ws + W2F_OFF);
  const _Float16* We1  = (const _Float16*)(ws + WE1_OFF);
  const _Float16* We2  = (const _Float16*)(ws + WE2_OFF);
  const _Float16* Wel  = (const _Float16*)(ws + WEL_OFF);
  const float* wihc = (const float*)(ws + WIHC_OFF);
  const float* bsum = (const float*)(ws + BSUM_OFF);
  const float* bhhn = (const float*)(ws + BHHN_OFF);
  const float* b1p  = (const float*)(ws + B1P_OFF);
  const float* b2p  = (const float*)(ws + B2P_OFF);
  const float* w3p  = (const float*)(ws + W3P_OFF);
  const float* be1  = (const float*)(ws + BE1_OFF);
  const float* be2  = (const float*)(ws + BE2_OFF);
  const float* bel  = (const float*)(ws + BEL_OFF);
  const float b3v   = *(const float*)(ws + B3_OFF);
  const double* ctg = (const double*)(ws + CT_OFF);

  const int tid = threadIdx.x;
  const int lane = tid & 63, wv = tid >> 6;     // 16 waves
  const int q = lane >> 4, c = lane & 15;
  const int lf = lane * 8;                      // lane's f16 offset inside a frag
  const int row0 = blockIdx.x * 256;
  const half8 Z8 = {};

  // ---------------- ENCODER: 4 sub-rounds of 64 rows, (jt,m)-unit parallel ----------------
#pragma unroll 1
  for (int sub = 0; sub < 4; ++sub) {
    float*    XF  = (float*)(smem + XF_OFF);               // [64][101]
    _Float16* X1  = (_Float16*)(smem + XF_OFF);            // [64][104] overlays after DFT
    _Float16* SIG = (_Float16*)(smem + SIG_OFF);           // [64][208]
    __syncthreads();
    for (int i = tid; i < 6400; i += 1024) {
      int r = i / 100, t = i - r * 100;
      XF[r * 101 + t] = enc_in[(size_t)(row0 + sub * 64 + r) * 100 + t];
    }
    if (tid < 384) {                                       // zero SIG pad cols 202..207
      int r = tid / 6; SIG[r * 208 + 202 + (tid - r * 6)] = (_Float16)0.f;
    }
    __syncthreads();
    // fp64 DFT; lane = row, wave-uniform bin; twiddles via SMEM-cached global
    for (int kb = wv; kb < 51; kb += 16) {
      double re = 0.0, im = 0.0; int m = 0;
      const float* xr = XF + lane * 101;
      for (int t = 0; t < 100; ++t) {
        double x = (double)xr[t];
        re = fma(x, ctg[2 * m], re);
        im = fma(x, ctg[2 * m + 1], im);
        m += kb; if (m >= 100) m -= 100;
      }
      if (kb == 0 || kb == 50) im = 0.0;
      float ab = (float)sqrt(re * re + im * im);
      float an = atan2f((float)im, (float)re);
      SIG[lane * 208 + 100 + kb] = (_Float16)ab;
      SIG[lane * 208 + 151 + kb] = (_Float16)an;
    }
    for (int i = tid; i < 6400; i += 1024) {
      int r = i / 100, t = i - r * 100;
      SIG[r * 208 + t] = (_Float16)XF[r * 101 + t];
    }
    __syncthreads();
    // enc1: sig(K208) -> x1 ; 28 (jt,m) units over 16 waves
#pragma unroll 1
    for (int u = wv; u < 28; u += 16) {
      int jt = u >> 2, m = u & 3;
      floatx4 C = {0, 0, 0, 0};
      const _Float16* wp = We1 + (jt * 16 + c) * 224 + q * 8;
#pragma unroll
      for (int s = 0; s < 7; ++s) {
        half8 B = g_frag(wp + s * 32);
        half8 Af = (s == 6 && q >= 2) ? Z8 : lds_frag16(SIG + (m * 16 + c) * 208 + q * 8 + s * 32);
        C = MFMA16(Af, B, C);
      }
      int col = jt * 16 + c; float bv = be1[col]; bool wm = col < 104;
#pragma unroll
      for (int r = 0; r < 4; ++r) {
        float v = C[r] + bv; v = fmaxf(v, 0.01f * v);
        if (wm) X1[(m * 16 + 4 * q + r) * 104 + col] = (_Float16)v;
      }
    }
    __syncthreads();
    // enc2: x1(K104) -> x2 (overlays SIG) ; 52 units
#pragma unroll 1
    for (int u = wv; u < 52; u += 16) {
      int jt = u >> 2, m = u & 3;
      floatx4 C = {0, 0, 0, 0};
      const _Float16* wp = We2 + (jt * 16 + c) * 128 + q * 8;
#pragma unroll
      for (int s = 0; s < 4; ++s) {
        half8 B = g_frag(wp + s * 32);
        half8 Af = (s == 3 && q >= 1) ? Z8 : lds_frag16(X1 + (m * 16 + c) * 104 + q * 8 + s * 32);
        C = MFMA16(Af, B, C);
      }
      int col = jt * 16 + c; float bv = be2[col];
#pragma unroll
      for (int r = 0; r < 4; ++r) {
        float v = C[r] + bv; v = fmaxf(v, 0.01f * v);
        SIG[(m * 16 + 4 * q + r) * 208 + col] = (_Float16)v;   // X2
      }
    }
    __syncthreads();
    // encl: x2(K208) -> h0 rows ; 52 units
#pragma unroll 1
    for (int u = wv; u < 52; u += 16) {
      int jt = u >> 2, m = u & 3;
      floatx4 C = {0, 0, 0, 0};
      const _Float16* wp = Wel + (jt * 16 + c) * 224 + q * 8;
#pragma unroll
      for (int s = 0; s < 7; ++s) {
        half8 B = g_frag(wp + s * 32);
        half8 Af = (s == 6 && q >= 2) ? Z8 : lds_frag16(SIG + (m * 16 + c) * 208 + q * 8 + s * 32);
        C = MFMA16(Af, B, C);
      }
      int col = jt * 16 + c; float bv = bel[col]; bool wm = col < 200;
#pragma unroll
      for (int r = 0; r < 4; ++r) {
        float v = C[r] + bv;
        if (wm) Hb[(sub * 64 + m * 16 + 4 * q + r) * 200 + col] = (_Float16)v;
      }
    }
  }
  __syncthreads();          // all encl writes done
  for (int i = tid; i < 256; i += 1024)
    DECIN[i] = enc_in[(size_t)(row0 + i) * 100 + 99];
  __syncthreads();          // encoder h0 + DECIN visible to all waves

  _Float16* myCHK = (_Float16*)(smem + CHK_OFF) + wv * 512;    // [16][32] f16, wave-private

  // ---------------- DECODER ----------------
#pragma unroll 1
  for (int k = 0; k <= 50; ++k) {
    // WB t0 prefetch at iter top (WB dead since prev y1; gate barriers since then)
    if (k >= 1)
      for (int i = wv; i < 7; i += 16)
        gload_lds16(WD1f + i * 512 + lf, WB0 + i * 512);

    // A-frags of h_k (own rows, wave-private). s==6,q>=2 masked: avoids over-read past
    // Hb row end (would hit neighbor rows / GB bytes -- possible NaN x 0 = NaN in MFMA).
    half8 A[7];
#pragma unroll
    for (int s = 0; s < 7; ++s)
      A[s] = (s == 6 && q >= 2) ? Z8 : lds_frag16(Hb + (wv * 16 + c) * 200 + s * 32 + q * 8);

    if (k >= 1) {
      // ---- y1: 7 dec_w1 tiles, LDS double-buffered; CHK transpose wave-private ----
      half8 A2[4];
      __syncthreads();                          // t0 staged
#pragma unroll
      for (int t = 0; t < 7; ++t) {
        if (t < 6) {
          _Float16* dst = ((t + 1) & 1) ? WB1 : WB0;
          for (int i = wv; i < 7; i += 16)
            gload_lds16(WD1f + (t + 1) * 3584 + i * 512 + lf, dst + i * 512);
        }
        const _Float16* wb_ = (t & 1) ? WB1 : WB0;
        floatx4 C = {0, 0, 0, 0};
#pragma unroll
        for (int s = 0; s < 7; ++s) {
          half8 B = lds_frag16(wb_ + s * 512 + lf);
          C = MFMA16(A[s], B, C);
        }
        int col = t * 16 + c; float bv = b1p[col];
#pragma unroll
        for (int r = 0; r < 4; ++r) {
          float v = C[r] + bv; v = fmaxf(v, 0.01f * v);
          myCHK[chk_idx(4 * q + r, (t & 1) * 16 + c)] = (_Float16)v;
        }
        if (t & 1) A2[t >> 1] = lds_frag16(myCHK + chk_idx(c, q * 8));
        if (t == 6) A2[3] = lds_frag16(myCHK + chk_idx(c, q * 8));  // q>=2 stale x zero-weight
        if (t < 6) __syncthreads();             // t+1 staged; WB[t&1] reads complete
      }
      // ---- y2 -> y3 (W2 frags from L2; 16 coalesced 1KB loads) ----
      float ya[4] = {0, 0, 0, 0};
#pragma unroll
      for (int jt2 = 0; jt2 < 4; ++jt2) {
        floatx4 Cy = {0, 0, 0, 0};
#pragma unroll
        for (int s2 = 0; s2 < 4; ++s2) {
          half8 B = g_frag(W2f + (jt2 * 4 + s2) * 512 + lf);
          Cy = MFMA16(A2[s2], B, Cy);
        }
        int col2 = jt2 * 16 + c; float b2v = b2p[col2], w3v = w3p[col2];
#pragma unroll
        for (int r = 0; r < 4; ++r) {
          float v = Cy[r] + b2v; v = fmaxf(v, 0.01f * v);
          ya[r] = fmaf(v, w3v, ya[r]);
        }
      }
#pragma unroll
      for (int r = 0; r < 4; ++r) {
        float v = ya[r];
        v += __shfl_xor(v, 1); v += __shfl_xor(v, 2);
        v += __shfl_xor(v, 4); v += __shfl_xor(v, 8);
        if (c == 0) {
          int rowL = wv * 16 + 4 * q + r;
          float y = v + b3v;
          DECIN[rowL] = y;                      // wave-private rows
          out[(size_t)(row0 + rowL) * 50 + (k - 1)] = y;
        }
      }
    }
    if (k <= 49) {
      // ---- 3-gate GEMM: 13 jt, single-buffered frag-linear tiles ----
      float dreg[4];
#pragma unroll
      for (int r = 0; r < 4; ++r)
        dreg[r] = DECIN[wv * 16 + 4 * q + r];   // same-wave write->read ordering
#pragma unroll 1
      for (int jt = 0; jt < 13; ++jt) {
        __syncthreads();                        // prev jt reads done (jt0: y-path done)
        for (int i = wv; i < 21; i += 16)
          gload_lds16(WJTp + jt * 10752 + i * 512 + lf, GB + i * 512);
        __syncthreads();                        // staged (barrier drains vmcnt)
        floatx4 Cr = {0, 0, 0, 0}, Cz = {0, 0, 0, 0}, Cn = {0, 0, 0, 0};
#pragma unroll
        for (int s = 0; s < 7; ++s) {
          half8 Br = lds_frag16(GB + s * 512 + lf);
          half8 Bz = lds_frag16(GB + (7 + s) * 512 + lf);
          half8 Bn = lds_frag16(GB + (14 + s) * 512 + lf);
          Cr = MFMA16(A[s], Br, Cr);
          Cz = MFMA16(A[s], Bz, Cz);
          Cn = MFMA16(A[s], Bn, Cn);
        }
        int col = jt * 16 + c;
        float wr = wihc[col], wz = wihc[208 + col], wn = wihc[416 + col];
        float br = bsum[col], bz = bsum[208 + col], bnih = bsum[416 + col];
        float bnhh = bhhn[col];
        bool wm = col < 200;
        _Float16* hp = Hb + (wv * 16 + 4 * q) * 200 + col;
#pragma unroll
        for (int r = 0; r < 4; ++r) {
          float d  = dreg[r];
          float ho = (float)hp[r * 200];
          float rgate = sigm(Cr[r] + fmaf(d, wr, br));
          float zgate = sigm(Cz[r] + fmaf(d, wz, bz));
          float ngate = tanh_(fmaf(d, wn, bnih) + rgate * (Cn[r] + bnhh));
          float hv = fmaf(zgate, ho - ngate, ngate);
          if (wm) hp[r * 200] = (_Float16)hv;
        }
      }
    }
  }
}

extern "C" void kernel_launch(void* const* d_in, const int* in_sizes, int n_in,
                              void* d_out, int out_size, void* d_ws, size_t ws_size,
                              hipStream_t stream) {
  const float* enc_in = (const float*)d_in[0];
  const float* enc_w1 = (const float*)d_in[1];
  const float* enc_b1 = (const float*)d_in[2];
  const float* enc_w2 = (const float*)d_in[3];
  const float* enc_b2 = (const float*)d_in[4];
  const float* enc_wl = (const float*)d_in[5];
  const float* enc_bl = (const float*)d_in[6];
  const float* w_ih   = (const float*)d_in[7];
  const float* w_hh   = (const float*)d_in[8];
  const float* b_ih   = (const float*)d_in[9];
  const float* b_hh   = (const float*)d_in[10];
  const float* dw1    = (const float*)d_in[11];
  const float* db1    = (const float*)d_in[12];
  const float* dw2    = (const float*)d_in[13];
  const float* db2    = (const float*)d_in[14];
  const float* dw3    = (const float*)d_in[15];
  const float* db3    = (const float*)d_in[16];
  unsigned char* ws = (unsigned char*)d_ws;
  float* out = (float*)d_out;

  prep_kernel<<<dim3(256), dim3(256), 0, stream>>>(
      enc_w1, enc_b1, enc_w2, enc_b2, enc_wl, enc_bl,
      w_ih, w_hh, b_ih, b_hh, dw1, db1, dw2, db2, dw3, db3, ws);
  fused_kernel<<<dim3(512), dim3(1024), 0, stream>>>(enc_in, ws, out);
}